// Round 1
// baseline (1327.301 us; speedup 1.0000x reference)
//
#include <hip/hip_runtime.h>
#include <hip/hip_bf16.h>
#include <cmath>

#define TOK 4097
#define BATCH 32
#define CH 256
#define NHEAD 8
#define HDIM 32
#define MROWS (BATCH*TOK)   // 131104
static constexpr float ATT_SCALE = 0.17677669529663687f;  // 32^-0.5

// ---------------- zero ----------------
__global__ void zero_kernel(float* __restrict__ p, int n) {
  int i = blockIdx.x*256 + threadIdx.x;
  if (i < n) p[i] = 0.f;
}

// ---------------- GEMM: C[M,Nout] = A[M,K] @ W[Nout,K]^T (+bias) ----------------
#define BM 128
#define BN 128
#define BKK 16
__global__ __launch_bounds__(256) void gemm_kernel(
    const float* __restrict__ A, const float* __restrict__ W,
    const float* __restrict__ bias, float* __restrict__ C,
    int Mtot, int Nout, int K)
{
  __shared__ float As[BKK][BM+4];
  __shared__ float Bs[BKK][BN+4];
  int tid = threadIdx.x;
  int m0 = blockIdx.x*BM, n0 = blockIdx.y*BN;
  int tm = (tid>>4)*8, tn = (tid&15)*8;
  float acc[8][8];
  #pragma unroll
  for (int i=0;i<8;i++)
    #pragma unroll
    for (int j=0;j<8;j++) acc[i][j]=0.f;

  for (int k0=0;k0<K;k0+=BKK) {
    #pragma unroll
    for (int i=0;i<2;i++) {
      int g = tid + i*256;
      int row = g>>2, c4 = g&3;
      float4 v = make_float4(0.f,0.f,0.f,0.f);
      if (m0+row < Mtot) v = *(const float4*)&A[(size_t)(m0+row)*K + k0 + c4*4];
      As[c4*4+0][row]=v.x; As[c4*4+1][row]=v.y; As[c4*4+2][row]=v.z; As[c4*4+3][row]=v.w;
    }
    #pragma unroll
    for (int i=0;i<2;i++) {
      int g = tid + i*256;
      int row=g>>2, c4=g&3;
      float4 v = *(const float4*)&W[(size_t)(n0+row)*K + k0 + c4*4];
      Bs[c4*4+0][row]=v.x; Bs[c4*4+1][row]=v.y; Bs[c4*4+2][row]=v.z; Bs[c4*4+3][row]=v.w;
    }
    __syncthreads();
    #pragma unroll
    for (int k=0;k<BKK;k++) {
      float a[8], bb[8];
      *(float4*)&a[0] = *(const float4*)&As[k][tm];
      *(float4*)&a[4] = *(const float4*)&As[k][tm+4];
      *(float4*)&bb[0] = *(const float4*)&Bs[k][tn];
      *(float4*)&bb[4] = *(const float4*)&Bs[k][tn+4];
      #pragma unroll
      for (int i=0;i<8;i++)
        #pragma unroll
        for (int j=0;j<8;j++) acc[i][j] += a[i]*bb[j];
    }
    __syncthreads();
  }
  float bv[8];
  #pragma unroll
  for (int j=0;j<8;j++) bv[j] = bias ? bias[n0+tn+j] : 0.f;
  #pragma unroll
  for (int i=0;i<8;i++) {
    int m = m0+tm+i;
    if (m < Mtot) {
      float4 o;
      o.x = acc[i][0]+bv[0]; o.y=acc[i][1]+bv[1]; o.z=acc[i][2]+bv[2]; o.w=acc[i][3]+bv[3];
      *(float4*)&C[(size_t)m*Nout + n0+tn] = o;
      o.x = acc[i][4]+bv[4]; o.y=acc[i][5]+bv[5]; o.z=acc[i][6]+bv[6]; o.w=acc[i][7]+bv[7];
      *(float4*)&C[(size_t)m*Nout + n0+tn+4] = o;
    }
  }
}

// ---------------- column sums over n: km, vm (from qkv), xm (from x) ----------------
__global__ void means_kernel(const float* __restrict__ x, const float* __restrict__ qkv,
                             float* __restrict__ kms, float* __restrict__ vms, float* __restrict__ xms)
{
  int b = blockIdx.y, chunk = blockIdx.x, c = threadIdx.x;
  float ksum=0.f, vsum=0.f, xsum=0.f;
  for (int n=chunk; n<TOK; n+=32) {
    size_t r = (size_t)b*TOK + n;
    ksum += qkv[r*768 + 256 + c];
    vsum += qkv[r*768 + 512 + c];
    xsum += x[r*256 + c];
  }
  atomicAdd(&kms[b*CH+c], ksum);
  atomicAdd(&vms[b*CH+c], vsum);
  atomicAdd(&xms[b*CH+c], xsum);
}

// ---------------- kv[b,h,d,e] raw sum over n of k_d * v_e ----------------
__global__ __launch_bounds__(256) void kv_kernel(const float* __restrict__ qkv, float* __restrict__ kvs)
{
  __shared__ float ks[64][32];
  __shared__ float vsd[64][32];
  int bh = blockIdx.x;
  int b = bh>>3, h = bh&7;
  int chunk = blockIdx.y;
  int nstart = chunk*1025;
  int nend = min(TOK, nstart+1025);
  int tid = threadIdx.x;
  int e = tid&31, dq = tid>>5;   // dq in [0,8): d-block of 4
  float acc[4] = {0.f,0.f,0.f,0.f};
  for (int n0=nstart; n0<nend; n0+=64) {
    int cnt = min(64, nend-n0);
    #pragma unroll
    for (int i=0;i<4;i++) {
      int g = tid + i*256;
      int token = g>>4, part = g&15;
      if (token < cnt) {
        size_t base = ((size_t)b*TOK + n0 + token)*768;
        if (part<8) *(float4*)&ks[token][part*4]      = *(const float4*)&qkv[base + 256 + h*HDIM + part*4];
        else        *(float4*)&vsd[token][(part-8)*4] = *(const float4*)&qkv[base + 512 + h*HDIM + (part-8)*4];
      }
    }
    __syncthreads();
    for (int t=0;t<cnt;t++) {
      float4 kk = *(const float4*)&ks[t][dq*4];
      float vv = vsd[t][e];
      acc[0]+=kk.x*vv; acc[1]+=kk.y*vv; acc[2]+=kk.z*vv; acc[3]+=kk.w*vv;
    }
    __syncthreads();
  }
  #pragma unroll
  for (int i=0;i<4;i++)
    atomicAdd(&kvs[((size_t)bh*HDIM + dq*4+i)*HDIM + e], acc[i]);
}

// ---------------- tiny grouped MLP -> per-sample 3x3 depthwise weights ----------------
__global__ __launch_bounds__(256) void mlp_kernel(const float* __restrict__ xms,
    const float* __restrict__ W1, const float* __restrict__ b1,
    const float* __restrict__ W2, const float* __restrict__ b2, float* __restrict__ rsw)
{
  __shared__ float xs[256];
  __shared__ float h1s[256];
  int b = blockIdx.x, tid = threadIdx.x;
  xs[tid] = xms[b*CH + tid] * (1.0f/(float)TOK);
  __syncthreads();
  int g = tid>>5, o = tid&31;
  float a = 0.f;
  #pragma unroll
  for (int k=0;k<32;k++) a += xs[g*32+k]*W1[(g*32+o)*32+k];
  a += b1[tid];
  // exact GELU: 0.5*x*(1+erf(x/sqrt(2)))
  h1s[tid] = 0.5f*a*(1.0f + erff(a*0.70710678118654752f));
  __syncthreads();
  for (int idx=tid; idx<2304; idx+=256) {
    int g2 = idx/288;
    float s = 0.f;
    const float* w2p = W2 + (size_t)idx*32;
    #pragma unroll
    for (int k=0;k<32;k++) s += h1s[g2*32+k]*w2p[k];
    s += b2[idx];
    rsw[(size_t)b*2304 + idx] = s;   // layout == w2 flat == [b][c][9]
  }
}

// ---------------- attention out + sliding-window depthwise conv -> pre ----------------
__global__ __launch_bounds__(256) void attn_kernel(
    const float* __restrict__ qkv, const float* __restrict__ kvs,
    const float* __restrict__ kms, const float* __restrict__ vms,
    const float* __restrict__ rsw, float* __restrict__ pre)
{
  __shared__ float qs[32][256];
  int b = blockIdx.y, yt = blockIdx.x;
  int c = threadIdx.x;
  int h = c>>5, e = c&31;
  const float invN = 1.0f/(float)TOK;
  const float s2 = ATT_SCALE*invN;

  float kve[32], kmr[32];
  {
    const float* kvp = kvs + (((size_t)(b*NHEAD+h))*HDIM)*HDIM + e;
    #pragma unroll
    for (int d=0; d<32; d++) kve[d] = kvp[(size_t)d*HDIM] * s2;   // s^2 * raw sum
    const float* kmp = kms + (size_t)b*CH + h*HDIM;
    #pragma unroll
    for (int d=0; d<32; d++) kmr[d] = kmp[d] * s2;                // scale * mean = (scale/N)*sum
  }
  float vme = vms[(size_t)b*CH + c] * invN;
  float wt[9];
  {
    const float* rwp = rsw + ((size_t)b*CH + c)*9;
    #pragma unroll
    for (int j=0;j<9;j++) wt[j]=rwp[j];
  }

  bool isCls = (yt==64);
  int y = yt;
  int t0 = isCls ? 0 : (1 + 64*y);
  const float* vb = qkv + ((size_t)b*TOK)*768 + 512 + c;  // v[b, t, c] at vb + t*768
  bool up = (y>0), dn = (y<63);
  float win[3][3];
  if (!isCls) {
    #pragma unroll
    for (int r=0;r<3;r++) {
      bool rok = (r==0)?up:((r==2)?dn:true);
      win[r][0] = 0.f;
      win[r][1] = rok ? vb[(size_t)(1+(y+r-1)*64+0)*768] : 0.f;
      win[r][2] = rok ? vb[(size_t)(1+(y+r-1)*64+1)*768] : 0.f;
    }
  }

  int nsub = isCls?1:2;
  for (int sub=0; sub<nsub; ++sub) {
    int tbase = t0 + sub*32;
    int cnt = isCls?1:32;
    __syncthreads();
    for (int g=threadIdx.x; g<cnt*64; g+=256) {
      int token=g>>6, c4=g&63;
      *(float4*)&qs[token][c4*4] = *(const float4*)&qkv[((size_t)b*TOK + tbase+token)*768 + c4*4];
    }
    __syncthreads();
    for (int xl=0; xl<cnt; ++xl) {
      int x = sub*32 + xl;
      float accA=0.f, accQ=0.f;
      #pragma unroll
      for (int d=0; d<32; d+=4) {
        float4 qv = *(const float4*)&qs[xl][h*HDIM + d];
        accA += qv.x*kve[d]+qv.y*kve[d+1]+qv.z*kve[d+2]+qv.w*kve[d+3];
        accQ += qv.x*kmr[d]+qv.y*kmr[d+1]+qv.z*kmr[d+2]+qv.w*kmr[d+3];
      }
      float outv = accA + (1.0f-accQ)*vme;
      if (!isCls) {
        #pragma unroll
        for (int r=0;r<3;r++)
          #pragma unroll
          for (int cc=0;cc<3;cc++) outv += win[r][cc]*wt[r*3+cc];
        #pragma unroll
        for (int r=0;r<3;r++){ win[r][0]=win[r][1]; win[r][1]=win[r][2]; }
        int xx = x+2;
        if (xx < 64) {
          #pragma unroll
          for (int r=0;r<3;r++) {
            bool rok = (r==0)?up:((r==2)?dn:true);
            win[r][2] = rok ? vb[(size_t)(1+(y+r-1)*64+xx)*768] : 0.f;
          }
        } else {
          win[0][2]=0.f; win[1][2]=0.f; win[2][2]=0.f;
        }
      }
      pre[((size_t)b*TOK + tbase + xl)*CH + c] = outv;
    }
  }
}

extern "C" void kernel_launch(void* const* d_in, const int* in_sizes, int n_in,
                              void* d_out, int out_size, void* d_ws, size_t ws_size,
                              hipStream_t stream)
{
  (void)in_sizes; (void)n_in; (void)out_size; (void)ws_size;
  const float* x     = (const float*)d_in[0];
  const float* Wqkv  = (const float*)d_in[1];
  const float* Wproj = (const float*)d_in[2];
  const float* bproj = (const float*)d_in[3];
  const float* W1    = (const float*)d_in[4];
  const float* b1    = (const float*)d_in[5];
  const float* W2    = (const float*)d_in[6];
  const float* b2    = (const float*)d_in[7];
  float* out = (float*)d_out;
  float* ws  = (float*)d_ws;

  float* qkv = ws;                                   // M*768 floats
  float* pre = qkv + (size_t)MROWS*768;              // M*256
  float* kvs = pre + (size_t)MROWS*256;              // 32*8*32*32
  float* kms = kvs + (size_t)BATCH*NHEAD*HDIM*HDIM;  // 32*256
  float* vms = kms + BATCH*CH;                       // 32*256
  float* xms = vms + BATCH*CH;                       // 32*256
  float* rsw = xms + BATCH*CH;                       // 32*2304

  int zn = BATCH*NHEAD*HDIM*HDIM + 3*BATCH*CH;       // zero atomic targets
  zero_kernel<<<dim3((zn+255)/256), 256, 0, stream>>>(kvs, zn);
  gemm_kernel<<<dim3((MROWS+BM-1)/BM, 768/BN), 256, 0, stream>>>(x, Wqkv, nullptr, qkv, MROWS, 768, 256);
  means_kernel<<<dim3(32, BATCH), 256, 0, stream>>>(x, qkv, kms, vms, xms);
  kv_kernel<<<dim3(BATCH*NHEAD, 4), 256, 0, stream>>>(qkv, kvs);
  mlp_kernel<<<dim3(BATCH), 256, 0, stream>>>(xms, W1, b1, W2, b2, rsw);
  attn_kernel<<<dim3(65, BATCH), 256, 0, stream>>>(qkv, kvs, kms, vms, rsw, pre);
  gemm_kernel<<<dim3((MROWS+BM-1)/BM, 256/BN), 256, 0, stream>>>(pre, Wproj, bproj, out, MROWS, 256, 256);
}